// Round 3
// baseline (816.734 us; speedup 1.0000x reference)
//
#include <hip/hip_runtime.h>
#include <hip/hip_bf16.h>
#include <stdint.h>

// AttentionReadout: G=1024 graphs x N=64 nodes, D=512, H=8, hd=64. fp32 I/O.
// v3: gate-factorized. Per-graph kernel computes ctx per head (bf16 -> ws) and
// gate logits via u = Wo^T gw; epilogue forms wctx = sum_n gate[n] ctx[n,:].
// Final out-projection is a separate small GEMM (weights amortized 32 graphs/block).
// No attn_out accumulators -> no register spills (round-2 lesson: 60 MB spill writes).

typedef __attribute__((ext_vector_type(8))) short short8;   // 8 bf16 (4 VGPRs)
typedef __attribute__((ext_vector_type(4))) float f32x4;    // MFMA C/D frag

#define H_  8
#define D_  512
#define N_  64

// ---- ws layout (bytes) ----
#define WQKV_OFF   0u          // 786432 bf16 = 1572864 B
#define WO_OFF     1572864u    // 262144 bf16 = 524288 B
#define U_OFF      2097152u    // 512 f32
#define C0_OFF     2099200u    // 1 f32
#define SG_OFF     2099264u    // 1024 f32
#define WCTX_OFF   2103360u    // 1024*512 bf16 = 1 MB   (16B aligned)
#define CTX_OFF    4194304u    // 65536*512 bf16 = 64 MB (16B aligned)
// total ws need: 71303168 B (~68 MB)

__device__ __forceinline__ unsigned short f2bf(float f) {
    union { float f; unsigned int u; } t; t.f = f;
    unsigned int u = t.u;
    return (unsigned short)((u + 0x7FFFu + ((u >> 16) & 1u)) >> 16);  // RNE
}

// ---- pre-pass 1: convert wqkv + wo fp32 -> bf16 ----
__global__ __launch_bounds__(256)
void convert_weights(const float* __restrict__ wqkv, const float* __restrict__ wo,
                     unsigned short* __restrict__ wbf) {
    const int i4 = blockIdx.x * 256 + threadIdx.x;          // float4 index, 262144 total
    float4 v;
    if (i4 < 196608) v = *(const float4*)(wqkv + (size_t)i4 * 4);
    else             v = *(const float4*)(wo   + (size_t)(i4 - 196608) * 4);
    unsigned short a0 = f2bf(v.x), a1 = f2bf(v.y), a2 = f2bf(v.z), a3 = f2bf(v.w);
    uint2 p; p.x = a0 | ((unsigned)a1 << 16); p.y = a2 | ((unsigned)a3 << 16);
    *(uint2*)(wbf + (size_t)i4 * 4) = p;
}

// ---- pre-pass 2: u = Wo^T gw (fp32), c0 = bo.gw + gb ----
__global__ __launch_bounds__(256)
void compute_u(const float* __restrict__ wo, const float* __restrict__ gw,
               const float* __restrict__ bo, const float* __restrict__ gb,
               float* __restrict__ u, float* __restrict__ c0) {
    const int t = threadIdx.x;
    float a0 = 0.f, a1 = 0.f;
    #pragma unroll 4
    for (int e = 0; e < 512; ++e) {
        const float ge = gw[e];
        a0 += wo[(size_t)e * 512 + t]       * ge;
        a1 += wo[(size_t)e * 512 + t + 256] * ge;
    }
    u[t] = a0; u[t + 256] = a1;
    __shared__ float rb[256];
    rb[t] = bo[t] * gw[t] + bo[t + 256] * gw[t + 256];
    __syncthreads();
    for (int s = 128; s > 0; s >>= 1) { if (t < s) rb[t] += rb[t + s]; __syncthreads(); }
    if (t == 0) c0[0] = rb[0] + gb[0];
}

// ---- main per-graph kernel: QKV + attention -> ctx(ws), gates, wctx(ws) ----
__global__ __launch_bounds__(256, 3)
void attn_ctx_kernel(const float* __restrict__ x,             // [65536,512] f32
                     const unsigned short* __restrict__ wqkv, // [1536,512] bf16
                     const float* __restrict__ bqkv,          // [1536] f32
                     const float* __restrict__ u,             // [512] f32
                     const float* __restrict__ c0,            // [1] f32
                     unsigned short* __restrict__ ctx_ws,     // [65536,512] bf16
                     unsigned short* __restrict__ wctx_ws,    // [1024,512] bf16
                     float* __restrict__ sumgate)             // [1024] f32
{
    __shared__ unsigned short xs[64][136];   // x slab [n][128 k + pad]
    __shared__ unsigned short qb[64][72];    // q [n][d]  -> later vT [d][n]
    __shared__ unsigned short kbuf[64][72];  // k [m][d]
    __shared__ unsigned short pb[64][72];    // P [n][m]
    __shared__ float logit[64];
    __shared__ float gatev[64];

    const int g    = blockIdx.x;
    const int tid  = threadIdx.x;
    const int w    = tid >> 6;      // wave 0..3
    const int lane = tid & 63;
    const int l15  = lane & 15;
    const int quad = lane >> 4;     // 0..3

    if (tid < 64) logit[tid] = 0.f;

    for (int h = 0; h < H_; ++h) {
        // ---- QKV (swapped): C'[d][n] = sum_k W[d][k] x[n][k], K=512 ----
        f32x4 qacc[4], kacc[4], vacc[4];
        #pragma unroll
        for (int i = 0; i < 4; ++i) {
            qacc[i] = (f32x4){0.f,0.f,0.f,0.f};
            kacc[i] = (f32x4){0.f,0.f,0.f,0.f};
            vacc[i] = (f32x4){0.f,0.f,0.f,0.f};
        }
        const unsigned short* wqrow = wqkv + (size_t)(h*64 + w*16 + l15) * D_;

        for (int kb = 0; kb < 4; ++kb) {
            __syncthreads();  // xs safe to overwrite
            #pragma unroll
            for (int i = 0; i < 8; ++i) {       // 2048 float4 / 256 thr
                int c4   = tid + i*256;
                int row  = c4 >> 5;
                int colf = (c4 & 31) << 2;
                float4 v = *(const float4*)(x + ((size_t)(g*64 + row))*D_ + kb*128 + colf);
                unsigned short a0 = f2bf(v.x), a1 = f2bf(v.y), a2 = f2bf(v.z), a3 = f2bf(v.w);
                uint2 p; p.x = a0 | ((unsigned)a1 << 16); p.y = a2 | ((unsigned)a3 << 16);
                *(uint2*)(&xs[row][colf]) = p;
            }
            __syncthreads();
            #pragma unroll
            for (int ks = 0; ks < 4; ++ks) {
                const int wcol = kb*128 + ks*32 + quad*8;
                short8 aq = *(const short8*)(wqrow + wcol);
                short8 ak = *(const short8*)(wqrow + (size_t)512*D_  + wcol);
                short8 av = *(const short8*)(wqrow + (size_t)1024*D_ + wcol);
                #pragma unroll
                for (int nt = 0; nt < 4; ++nt) {
                    short8 bx = *(const short8*)(&xs[nt*16 + l15][ks*32 + quad*8]);
                    qacc[nt] = __builtin_amdgcn_mfma_f32_16x16x32_bf16(aq, bx, qacc[nt], 0, 0, 0);
                    kacc[nt] = __builtin_amdgcn_mfma_f32_16x16x32_bf16(ak, bx, kacc[nt], 0, 0, 0);
                    vacc[nt] = __builtin_amdgcn_mfma_f32_16x16x32_bf16(av, bx, vacc[nt], 0, 0, 0);
                }
            }
        }

        // store q,k (+bias) to LDS [n][d]
        {
            const int dbase = h*64 + w*16 + quad*4;
            #pragma unroll
            for (int nt = 0; nt < 4; ++nt) {
                unsigned short tq[4], tk[4];
                #pragma unroll
                for (int r = 0; r < 4; ++r) {
                    tq[r] = f2bf(qacc[nt][r] + bqkv[dbase + r]);
                    tk[r] = f2bf(kacc[nt][r] + bqkv[512 + dbase + r]);
                }
                uint2 vq; vq.x = tq[0] | ((unsigned)tq[1] << 16); vq.y = tq[2] | ((unsigned)tq[3] << 16);
                uint2 vk; vk.x = tk[0] | ((unsigned)tk[1] << 16); vk.y = tk[2] | ((unsigned)tk[3] << 16);
                *(uint2*)(&qb  [nt*16 + l15][w*16 + quad*4]) = vq;
                *(uint2*)(&kbuf[nt*16 + l15][w*16 + quad*4]) = vk;
            }
        }
        __syncthreads();

        // ---- scores + softmax; wave w owns rows [w*16, w*16+16) ----
        f32x4 sacc[4];
        #pragma unroll
        for (int i = 0; i < 4; ++i) sacc[i] = (f32x4){0.f,0.f,0.f,0.f};
        #pragma unroll
        for (int ks = 0; ks < 2; ++ks) {
            short8 aq = *(const short8*)(&qb[w*16 + l15][ks*32 + quad*8]);
            #pragma unroll
            for (int mt = 0; mt < 4; ++mt) {
                short8 bk = *(const short8*)(&kbuf[mt*16 + l15][ks*32 + quad*8]);
                sacc[mt] = __builtin_amdgcn_mfma_f32_16x16x32_bf16(aq, bk, sacc[mt], 0, 0, 0);
            }
        }
        float pv[4][4];
        #pragma unroll
        for (int r = 0; r < 4; ++r) {
            float m0 = -1e30f;
            #pragma unroll
            for (int mt = 0; mt < 4; ++mt) { pv[mt][r] = sacc[mt][r] * 0.125f; m0 = fmaxf(m0, pv[mt][r]); }
            m0 = fmaxf(m0, __shfl_xor(m0, 1));
            m0 = fmaxf(m0, __shfl_xor(m0, 2));
            m0 = fmaxf(m0, __shfl_xor(m0, 4));
            m0 = fmaxf(m0, __shfl_xor(m0, 8));
            float s = 0.f;
            #pragma unroll
            for (int mt = 0; mt < 4; ++mt) { float e = __expf(pv[mt][r] - m0); pv[mt][r] = e; s += e; }
            s += __shfl_xor(s, 1); s += __shfl_xor(s, 2); s += __shfl_xor(s, 4); s += __shfl_xor(s, 8);
            float inv = 1.0f / s;
            #pragma unroll
            for (int mt = 0; mt < 4; ++mt) pv[mt][r] *= inv;
        }
        #pragma unroll
        for (int mt = 0; mt < 4; ++mt)
            #pragma unroll
            for (int r = 0; r < 4; ++r)
                pb[w*16 + quad*4 + r][mt*16 + l15] = f2bf(pv[mt][r]);
        __syncthreads();  // P visible; q dead

        // store v^T (+bias) into qb: vT[d][n]
        {
            const int dbase = 1024 + h*64 + w*16 + quad*4;
            #pragma unroll
            for (int nt = 0; nt < 4; ++nt)
                #pragma unroll
                for (int r = 0; r < 4; ++r)
                    qb[w*16 + quad*4 + r][nt*16 + l15] = f2bf(vacc[nt][r] + bqkv[dbase + r]);
        }
        __syncthreads();  // vT visible

        // ---- ctx[n][d] = P @ v ----
        f32x4 cacc[4];
        #pragma unroll
        for (int i = 0; i < 4; ++i) cacc[i] = (f32x4){0.f,0.f,0.f,0.f};
        #pragma unroll
        for (int ks = 0; ks < 2; ++ks) {
            short8 ap = *(const short8*)(&pb[w*16 + l15][ks*32 + quad*8]);
            #pragma unroll
            for (int dt = 0; dt < 4; ++dt) {
                short8 bv = *(const short8*)(&qb[dt*16 + l15][ks*32 + quad*8]);
                cacc[dt] = __builtin_amdgcn_mfma_f32_16x16x32_bf16(ap, bv, cacc[dt], 0, 0, 0);
            }
        }

        // ---- ctx -> ws (bf16) + gate-logit partials (no out-proj here) ----
        {
            float uv[4];
            #pragma unroll
            for (int dt = 0; dt < 4; ++dt) uv[dt] = u[h*64 + dt*16 + l15];
            const int nrow = w*16 + quad*4;
            #pragma unroll
            for (int r = 0; r < 4; ++r) {
                float s = 0.f;
                #pragma unroll
                for (int dt = 0; dt < 4; ++dt) {
                    s += cacc[dt][r] * uv[dt];
                    ctx_ws[((size_t)(g*64 + nrow + r))*D_ + h*64 + dt*16 + l15] = f2bf(cacc[dt][r]);
                }
                s += __shfl_xor(s, 1); s += __shfl_xor(s, 2);
                s += __shfl_xor(s, 4); s += __shfl_xor(s, 8);
                if (l15 == 0) logit[nrow + r] += s;
            }
        }
        // next head's first kb-barrier protects xs/qb/kbuf/pb
    }

    __threadfence();   // make ctx_ws stores visible before cross-wave reads
    __syncthreads();   // logit complete

    if (tid < 64) {
        float lg = logit[tid] + c0[0];
        float gt = 1.0f / (1.0f + __expf(-lg));
        gatev[tid] = gt;
        float s = gt;
        s += __shfl_xor(s, 1);  s += __shfl_xor(s, 2);  s += __shfl_xor(s, 4);
        s += __shfl_xor(s, 8);  s += __shfl_xor(s, 16); s += __shfl_xor(s, 32);
        if (tid == 0) sumgate[g] = s;
    }
    __syncthreads();

    // ---- wctx[d] = sum_n gate[n] * ctx[n][d]; thread owns d = {2t, 2t+1} ----
    {
        const unsigned int* ctxu = (const unsigned int*)ctx_ws + (size_t)g * 64 * 256;
        float a0 = 0.f, a1 = 0.f;
        #pragma unroll 8
        for (int n = 0; n < 64; ++n) {
            const float gn = gatev[n];
            unsigned int cw = ctxu[n*256 + tid];
            union { unsigned int u; float f; } t0, t1;
            t0.u = cw << 16; t1.u = cw & 0xFFFF0000u;
            a0 += gn * t0.f; a1 += gn * t1.f;
        }
        unsigned short b0 = f2bf(a0), b1 = f2bf(a1);
        ((unsigned int*)wctx_ws)[(size_t)g*256 + tid] = b0 | ((unsigned)b1 << 16);
    }
}

// ---- final out-projection: out[g][e] = wctx[g,:].Wo[e,:] + sumgate[g]*bo[e] ----
// 32 blocks x 32 graphs each; weights read 32x total instead of 1024x.
__global__ __launch_bounds__(256, 4)
void outproj_kernel(const unsigned short* __restrict__ wo_bf,   // [512,512] bf16
                    const unsigned short* __restrict__ wctx_bf, // [1024,512] bf16
                    const float* __restrict__ bo,               // [512] f32
                    const float* __restrict__ sumgate,          // [1024] f32
                    float* __restrict__ out)                    // [1024,512] f32
{
    const int tid  = threadIdx.x;
    const int w    = tid >> 6;
    const int lane = tid & 63;
    const int l15  = lane & 15;
    const int quad = lane >> 4;
    const int g0   = blockIdx.x * 32;

    f32x4 oac[8][2];
    #pragma unroll
    for (int et = 0; et < 8; ++et)
        #pragma unroll
        for (int mt = 0; mt < 2; ++mt)
            oac[et][mt] = (f32x4){0.f,0.f,0.f,0.f};

    #pragma unroll 4
    for (int ks = 0; ks < 16; ++ks) {
        const int col = ks*32 + quad*8;
        short8 a0 = *(const short8*)(wctx_bf + (size_t)(g0 + l15)*D_      + col);
        short8 a1 = *(const short8*)(wctx_bf + (size_t)(g0 + 16 + l15)*D_ + col);
        #pragma unroll
        for (int et = 0; et < 8; ++et) {
            short8 b = *(const short8*)(wo_bf + (size_t)(w*128 + et*16 + l15)*D_ + col);
            oac[et][0] = __builtin_amdgcn_mfma_f32_16x16x32_bf16(a0, b, oac[et][0], 0, 0, 0);
            oac[et][1] = __builtin_amdgcn_mfma_f32_16x16x32_bf16(a1, b, oac[et][1], 0, 0, 0);
        }
    }

    #pragma unroll
    for (int et = 0; et < 8; ++et) {
        const int e = w*128 + et*16 + l15;
        const float bov = bo[e];
        #pragma unroll
        for (int mt = 0; mt < 2; ++mt) {
            #pragma unroll
            for (int r = 0; r < 4; ++r) {
                const int gg = g0 + mt*16 + quad*4 + r;
                out[(size_t)gg*D_ + e] = oac[et][mt][r] + sumgate[gg] * bov;
            }
        }
    }
}

extern "C" void kernel_launch(void* const* d_in, const int* in_sizes, int n_in,
                              void* d_out, int out_size, void* d_ws, size_t ws_size,
                              hipStream_t stream) {
    const float* x    = (const float*)d_in[0];
    // d_in[1] = batch (int64) — unused: graphs are equal-sized (64 nodes)
    const float* wqkv = (const float*)d_in[2];
    const float* bqkv = (const float*)d_in[3];
    const float* wo   = (const float*)d_in[4];
    const float* bo   = (const float*)d_in[5];
    const float* gw   = (const float*)d_in[6];
    const float* gb   = (const float*)d_in[7];
    float* out = (float*)d_out;

    char* ws = (char*)d_ws;
    unsigned short* wqkv_bf = (unsigned short*)(ws + WQKV_OFF);
    unsigned short* wo_bf   = (unsigned short*)(ws + WO_OFF);
    float*          u_ws    = (float*)(ws + U_OFF);
    float*          c0_ws   = (float*)(ws + C0_OFF);
    float*          sg_ws   = (float*)(ws + SG_OFF);
    unsigned short* wctx_ws = (unsigned short*)(ws + WCTX_OFF);
    unsigned short* ctx_ws  = (unsigned short*)(ws + CTX_OFF);

    const int total = in_sizes[0] / D_;  // 65536 nodes
    const int G     = total / N_;        // 1024 graphs

    hipLaunchKernelGGL(convert_weights, dim3(1024), dim3(256), 0, stream, wqkv, wo, wqkv_bf);
    hipLaunchKernelGGL(compute_u, dim3(1), dim3(256), 0, stream, wo, gw, bo, gb, u_ws, c0_ws);
    hipLaunchKernelGGL(attn_ctx_kernel, dim3(G), dim3(256), 0, stream,
                       x, wqkv_bf, bqkv, u_ws, c0_ws, ctx_ws, wctx_ws, sg_ws);
    hipLaunchKernelGGL(outproj_kernel, dim3(G / 32), dim3(256), 0, stream,
                       wo_bf, wctx_ws, bo, sg_ws, out);
}

// Round 4
// 511.398 us; speedup vs baseline: 1.5971x; 1.5971x over previous
//
#include <hip/hip_runtime.h>
#include <stdint.h>

// AttentionReadout: G=1024 x N=64, D=512, H=8, hd=64. fp32 I/O, bf16 MFMA.
// v4: one 512-thread block per graph; x staged to LDS ONCE (149 KB LDS, CDNA4);
// heads processed in pairs (all 8 waves busy); ctx kept in registers; gate
// logits via u = Wo^T gw; only wctx (1 MB) leaves the kernel. Out-projection
// is a separate 32-block GEMM.

typedef __attribute__((ext_vector_type(8))) short short8;   // 8 bf16
typedef __attribute__((ext_vector_type(4))) float f32x4;    // MFMA C/D frag

#define D_ 512

// ---- ws layout (bytes) ----
#define WQKV_OFF   0u          // 1536*512 bf16 = 1572864
#define WO_OFF     1572864u    // 512*512 bf16  = 524288
#define UPART_OFF  2097152u    // 16*512 f32    = 32768
#define U_OFF      2129920u    // 512 f32       = 2048
#define C0_OFF     2131968u    // 64
#define SG_OFF     2132032u    // 1024 f32      = 4096
#define WCTX_OFF   2136128u    // 1024*512 bf16 = 1 MB (16B aligned)
// total ~3.2 MB

__device__ __forceinline__ unsigned short f2bf(float f) {
    union { float f; unsigned int u; } t; t.f = f;
    unsigned int u = t.u;
    return (unsigned short)((u + 0x7FFFu + ((u >> 16) & 1u)) >> 16);  // RNE
}

// ---- pre-pass 1: wqkv + wo fp32 -> bf16 ----
__global__ __launch_bounds__(256)
void convert_weights(const float* __restrict__ wqkv, const float* __restrict__ wo,
                     unsigned short* __restrict__ wbf) {
    const int i4 = blockIdx.x * 256 + threadIdx.x;          // 262144 float4 total
    float4 v;
    if (i4 < 196608) v = *(const float4*)(wqkv + (size_t)i4 * 4);
    else             v = *(const float4*)(wo   + (size_t)(i4 - 196608) * 4);
    unsigned short a0 = f2bf(v.x), a1 = f2bf(v.y), a2 = f2bf(v.z), a3 = f2bf(v.w);
    uint2 p; p.x = a0 | ((unsigned)a1 << 16); p.y = a2 | ((unsigned)a3 << 16);
    *(uint2*)(wbf + (size_t)i4 * 4) = p;
}

// ---- pre-pass 2a: u partials (16 blocks, e-split, coalesced row reads) ----
__global__ __launch_bounds__(256)
void compute_u_partial(const float* __restrict__ wo, const float* __restrict__ gw,
                       float* __restrict__ upart) {
    const int b = blockIdx.x;         // 16
    const int t = threadIdx.x;
    float a0 = 0.f, a1 = 0.f;
    #pragma unroll 4
    for (int e = b * 32; e < b * 32 + 32; ++e) {
        const float ge = gw[e];
        a0 += wo[(size_t)e * 512 + t]       * ge;
        a1 += wo[(size_t)e * 512 + t + 256] * ge;
    }
    upart[b * 512 + t] = a0; upart[b * 512 + t + 256] = a1;
}

// ---- pre-pass 2b: u = sum partials; c0 = bo.gw + gb ----
__global__ __launch_bounds__(256)
void finalize_u(const float* __restrict__ upart, const float* __restrict__ bo,
                const float* __restrict__ gw, const float* __restrict__ gb,
                float* __restrict__ u, float* __restrict__ c0) {
    const int t = threadIdx.x;
    float s0 = 0.f, s1 = 0.f;
    #pragma unroll
    for (int b = 0; b < 16; ++b) { s0 += upart[b*512 + t]; s1 += upart[b*512 + t + 256]; }
    u[t] = s0; u[t + 256] = s1;
    __shared__ float rb[256];
    rb[t] = bo[t] * gw[t] + bo[t + 256] * gw[t + 256];
    __syncthreads();
    for (int s = 128; s > 0; s >>= 1) { if (t < s) rb[t] += rb[t + s]; __syncthreads(); }
    if (t == 0) c0[0] = rb[0] + gb[0];
}

// ---- main: per-graph QKV + attention -> gates, wctx ----
__global__ __launch_bounds__(512, 2)
void attn_ctx_kernel(const float* __restrict__ x,             // [65536,512] f32
                     const unsigned short* __restrict__ wqkv, // [1536,512] bf16
                     const float* __restrict__ bqkv,          // [1536] f32
                     const float* __restrict__ u,             // [512] f32
                     const float* __restrict__ c0,            // [1] f32
                     unsigned short* __restrict__ wctx_ws,    // [1024,512] bf16
                     float* __restrict__ sumgate)             // [1024] f32
{
    __shared__ unsigned short xs[64][520];      // 66560 B, stride 1040B: conflict-free b128
    __shared__ unsigned short qbuf[2][64][72];  // 18432 B  q[head][n][d]
    __shared__ unsigned short kbuf[2][64][72];  // 18432 B  k[head][m][d]
    __shared__ unsigned short vbuf[2][64][72];  // 18432 B  vT[head][d][n]
    __shared__ unsigned short pbuf[2][64][72];  // 18432 B  P[head][n][m]
    __shared__ float fbuf[4][512];              // 8192 B   gated-ctx partials
    __shared__ float logit2[2][64];
    __shared__ float gatev[64];
    // total ~149.3 KB -> 1 block/CU, 8 waves

    const int g    = blockIdx.x;
    const int tid  = threadIdx.x;
    const int w    = tid >> 6;      // wave 0..7
    const int lane = tid & 63;
    const int l15  = lane & 15;
    const int quad = lane >> 4;

    // ---- stage x once: fp32 -> bf16 LDS ----
    #pragma unroll
    for (int i = 0; i < 16; ++i) {
        int idx = tid + i * 512;            // 8192 float4
        int row = idx >> 7;                 // 128 float4 per row
        int c4  = idx & 127;
        float4 v = *(const float4*)(x + ((size_t)(g*64 + row))*512 + c4*4);
        unsigned short a0 = f2bf(v.x), a1 = f2bf(v.y), a2 = f2bf(v.z), a3 = f2bf(v.w);
        uint2 p; p.x = a0 | ((unsigned)a1 << 16); p.y = a2 | ((unsigned)a3 << 16);
        *(uint2*)(&xs[row][c4*4]) = p;
    }
    if (tid < 128) ((float*)logit2)[tid] = 0.f;

    const int hs2  = w >> 2;         // head-slot this wave handles in attention
    const int row0 = (w & 3) << 4;   // its 16-row strip
    f32x4 cctx[4][4];                // ctx frags: [head-pair][dt]

    for (int hp = 0; hp < 4; ++hp) {
        __syncthreads();  // bufs safe to overwrite (also covers x-stage at hp=0)

        // ---- QKV: 24 row-tiles (q/k/v x 2 heads x 4), wave w owns tiles w*3+j ----
        f32x4 acc[3][4];
        #pragma unroll
        for (int j = 0; j < 3; ++j)
            #pragma unroll
            for (int nt = 0; nt < 4; ++nt) acc[j][nt] = (f32x4){0.f,0.f,0.f,0.f};

        int mj[3], hsj[3], rtj[3];
        const unsigned short* wr[3];
        #pragma unroll
        for (int j = 0; j < 3; ++j) {
            int t_ = w*3 + j;
            int c  = t_ >> 2; rtj[j] = t_ & 3;
            mj[j]  = c >> 1;  hsj[j] = c & 1;            // m: 0=q 1=k 2=v
            int head = hp*2 + hsj[j];
            wr[j] = wqkv + (size_t)(mj[j]*512 + head*64 + rtj[j]*16 + l15) * 512;
        }
        #pragma unroll 4
        for (int ks = 0; ks < 16; ++ks) {
            const int col = ks*32 + quad*8;
            short8 a0 = *(const short8*)(wr[0] + col);
            short8 a1 = *(const short8*)(wr[1] + col);
            short8 a2 = *(const short8*)(wr[2] + col);
            #pragma unroll
            for (int nt = 0; nt < 4; ++nt) {
                short8 b = *(const short8*)(&xs[nt*16 + l15][col]);
                acc[0][nt] = __builtin_amdgcn_mfma_f32_16x16x32_bf16(a0, b, acc[0][nt], 0,0,0);
                acc[1][nt] = __builtin_amdgcn_mfma_f32_16x16x32_bf16(a1, b, acc[1][nt], 0,0,0);
                acc[2][nt] = __builtin_amdgcn_mfma_f32_16x16x32_bf16(a2, b, acc[2][nt], 0,0,0);
            }
        }
        // write q,k ([n][d], packed) / v (transposed [d][n]) with bias
        #pragma unroll
        for (int j = 0; j < 3; ++j) {
            const int head  = hp*2 + hsj[j];
            const int dbase = mj[j]*512 + head*64 + rtj[j]*16 + quad*4;
            if (mj[j] == 2) {
                #pragma unroll
                for (int nt = 0; nt < 4; ++nt)
                    #pragma unroll
                    for (int r = 0; r < 4; ++r)
                        vbuf[hsj[j]][rtj[j]*16 + quad*4 + r][nt*16 + l15] =
                            f2bf(acc[j][nt][r] + bqkv[dbase + r]);
            } else {
                unsigned short (*dst)[72] = (mj[j] == 0) ? qbuf[hsj[j]] : kbuf[hsj[j]];
                #pragma unroll
                for (int nt = 0; nt < 4; ++nt) {
                    unsigned short tv[4];
                    #pragma unroll
                    for (int r = 0; r < 4; ++r) tv[r] = f2bf(acc[j][nt][r] + bqkv[dbase + r]);
                    uint2 pk; pk.x = tv[0] | ((unsigned)tv[1] << 16);
                    pk.y = tv[2] | ((unsigned)tv[3] << 16);
                    *(uint2*)(&dst[nt*16 + l15][rtj[j]*16 + quad*4]) = pk;
                }
            }
        }
        __syncthreads();

        // ---- scores + softmax: wave w -> head hs2, rows [row0, row0+16) ----
        f32x4 sacc[4];
        #pragma unroll
        for (int i = 0; i < 4; ++i) sacc[i] = (f32x4){0.f,0.f,0.f,0.f};
        #pragma unroll
        for (int ks = 0; ks < 2; ++ks) {
            short8 aq = *(const short8*)(&qbuf[hs2][row0 + l15][ks*32 + quad*8]);
            #pragma unroll
            for (int mt = 0; mt < 4; ++mt) {
                short8 bk = *(const short8*)(&kbuf[hs2][mt*16 + l15][ks*32 + quad*8]);
                sacc[mt] = __builtin_amdgcn_mfma_f32_16x16x32_bf16(aq, bk, sacc[mt], 0,0,0);
            }
        }
        float pv[4][4];
        #pragma unroll
        for (int r = 0; r < 4; ++r) {
            float m0 = -1e30f;
            #pragma unroll
            for (int mt = 0; mt < 4; ++mt) { pv[mt][r] = sacc[mt][r] * 0.125f; m0 = fmaxf(m0, pv[mt][r]); }
            m0 = fmaxf(m0, __shfl_xor(m0, 1));
            m0 = fmaxf(m0, __shfl_xor(m0, 2));
            m0 = fmaxf(m0, __shfl_xor(m0, 4));
            m0 = fmaxf(m0, __shfl_xor(m0, 8));
            float s = 0.f;
            #pragma unroll
            for (int mt = 0; mt < 4; ++mt) { float e = __expf(pv[mt][r] - m0); pv[mt][r] = e; s += e; }
            s += __shfl_xor(s, 1); s += __shfl_xor(s, 2); s += __shfl_xor(s, 4); s += __shfl_xor(s, 8);
            float inv = 1.0f / s;
            #pragma unroll
            for (int mt = 0; mt < 4; ++mt) pv[mt][r] *= inv;
        }
        #pragma unroll
        for (int mt = 0; mt < 4; ++mt)
            #pragma unroll
            for (int r = 0; r < 4; ++r)
                pbuf[hs2][row0 + quad*4 + r][mt*16 + l15] = f2bf(pv[mt][r]);
        __syncthreads();

        // ---- PV: ctx[n][d] = P @ v ----
        f32x4 cacc[4];
        #pragma unroll
        for (int i = 0; i < 4; ++i) cacc[i] = (f32x4){0.f,0.f,0.f,0.f};
        #pragma unroll
        for (int ks = 0; ks < 2; ++ks) {
            short8 ap = *(const short8*)(&pbuf[hs2][row0 + l15][ks*32 + quad*8]);
            #pragma unroll
            for (int dt = 0; dt < 4; ++dt) {
                short8 bv = *(const short8*)(&vbuf[hs2][dt*16 + l15][ks*32 + quad*8]);
                cacc[dt] = __builtin_amdgcn_mfma_f32_16x16x32_bf16(ap, bv, cacc[dt], 0,0,0);
            }
        }
        // gate-logit partials (fp32 ctx . u), ctx stays in registers
        {
            const int head2 = hp*2 + hs2;
            float uv[4];
            #pragma unroll
            for (int dt = 0; dt < 4; ++dt) uv[dt] = u[head2*64 + dt*16 + l15];
            #pragma unroll
            for (int r = 0; r < 4; ++r) {
                float s = cacc[0][r]*uv[0] + cacc[1][r]*uv[1] + cacc[2][r]*uv[2] + cacc[3][r]*uv[3];
                s += __shfl_xor(s, 1); s += __shfl_xor(s, 2);
                s += __shfl_xor(s, 4); s += __shfl_xor(s, 8);
                if (l15 == 0) logit2[hs2][row0 + quad*4 + r] += s;  // wave-exclusive slots
            }
        }
        #pragma unroll
        for (int dt = 0; dt < 4; ++dt) cctx[hp][dt] = cacc[dt];
    }

    __syncthreads();   // logit2 complete
    if (tid < 64) {
        float lg = logit2[0][tid] + logit2[1][tid] + c0[0];
        float gt = 1.0f / (1.0f + __expf(-lg));
        gatev[tid] = gt;
        float s = gt;
        s += __shfl_xor(s, 1);  s += __shfl_xor(s, 2);  s += __shfl_xor(s, 4);
        s += __shfl_xor(s, 8);  s += __shfl_xor(s, 16); s += __shfl_xor(s, 32);
        if (tid == 0) sumgate[g] = s;
    }
    __syncthreads();

    // ---- gated reduction from register ctx: wctx[d] = sum_n gate[n] ctx[n][d] ----
    {
        float gv[4];
        #pragma unroll
        for (int r = 0; r < 4; ++r) gv[r] = gatev[row0 + quad*4 + r];
        #pragma unroll
        for (int hp = 0; hp < 4; ++hp) {
            const int head2 = hp*2 + hs2;
            #pragma unroll
            for (int dt = 0; dt < 4; ++dt) {
                float s = cctx[hp][dt][0]*gv[0] + cctx[hp][dt][1]*gv[1]
                        + cctx[hp][dt][2]*gv[2] + cctx[hp][dt][3]*gv[3];
                s += __shfl_xor(s, 16); s += __shfl_xor(s, 32);   // sum over quads
                if (lane < 16) fbuf[w & 3][head2*64 + dt*16 + lane] = s;
            }
        }
    }
    __syncthreads();
    {
        float vs = fbuf[0][tid] + fbuf[1][tid] + fbuf[2][tid] + fbuf[3][tid];
        wctx_ws[(size_t)g*512 + tid] = f2bf(vs);
    }
}

// ---- final out-projection: out[g][e] = wctx[g,:].Wo[e,:] + sumgate[g]*bo[e] ----
__global__ __launch_bounds__(256, 4)
void outproj_kernel(const unsigned short* __restrict__ wo_bf,   // [512,512] bf16
                    const unsigned short* __restrict__ wctx_bf, // [1024,512] bf16
                    const float* __restrict__ bo,               // [512] f32
                    const float* __restrict__ sumgate,          // [1024] f32
                    float* __restrict__ out)                    // [1024,512] f32
{
    const int tid  = threadIdx.x;
    const int w    = tid >> 6;
    const int lane = tid & 63;
    const int l15  = lane & 15;
    const int quad = lane >> 4;
    const int g0   = blockIdx.x * 32;

    f32x4 oac[8][2];
    #pragma unroll
    for (int et = 0; et < 8; ++et)
        #pragma unroll
        for (int mt = 0; mt < 2; ++mt)
            oac[et][mt] = (f32x4){0.f,0.f,0.f,0.f};

    #pragma unroll 4
    for (int ks = 0; ks < 16; ++ks) {
        const int col = ks*32 + quad*8;
        short8 a0 = *(const short8*)(wctx_bf + (size_t)(g0 + l15)*D_      + col);
        short8 a1 = *(const short8*)(wctx_bf + (size_t)(g0 + 16 + l15)*D_ + col);
        #pragma unroll
        for (int et = 0; et < 8; ++et) {
            short8 b = *(const short8*)(wo_bf + (size_t)(w*128 + et*16 + l15)*D_ + col);
            oac[et][0] = __builtin_amdgcn_mfma_f32_16x16x32_bf16(a0, b, oac[et][0], 0,0,0);
            oac[et][1] = __builtin_amdgcn_mfma_f32_16x16x32_bf16(a1, b, oac[et][1], 0,0,0);
        }
    }
    #pragma unroll
    for (int et = 0; et < 8; ++et) {
        const int e = w*128 + et*16 + l15;
        const float bov = bo[e];
        #pragma unroll
        for (int mt = 0; mt < 2; ++mt)
            #pragma unroll
            for (int r = 0; r < 4; ++r) {
                const int gg = g0 + mt*16 + quad*4 + r;
                out[(size_t)gg*D_ + e] = oac[et][mt][r] + sumgate[gg] * bov;
            }
    }
}

extern "C" void kernel_launch(void* const* d_in, const int* in_sizes, int n_in,
                              void* d_out, int out_size, void* d_ws, size_t ws_size,
                              hipStream_t stream) {
    const float* x    = (const float*)d_in[0];
    // d_in[1] = batch (int64) — unused: graphs are equal-sized (64 nodes)
    const float* wqkv = (const float*)d_in[2];
    const float* bqkv = (const float*)d_in[3];
    const float* wo   = (const float*)d_in[4];
    const float* bo   = (const float*)d_in[5];
    const float* gw   = (const float*)d_in[6];
    const float* gb   = (const float*)d_in[7];
    float* out = (float*)d_out;

    char* ws = (char*)d_ws;
    unsigned short* wqkv_bf = (unsigned short*)(ws + WQKV_OFF);
    unsigned short* wo_bf   = (unsigned short*)(ws + WO_OFF);
    float*          upart   = (float*)(ws + UPART_OFF);
    float*          u_ws    = (float*)(ws + U_OFF);
    float*          c0_ws   = (float*)(ws + C0_OFF);
    float*          sg_ws   = (float*)(ws + SG_OFF);
    unsigned short* wctx_ws = (unsigned short*)(ws + WCTX_OFF);

    const int total = in_sizes[0] / D_;  // 65536 nodes
    const int G     = total / 64;        // 1024 graphs

    hipLaunchKernelGGL(convert_weights,   dim3(1024), dim3(256), 0, stream, wqkv, wo, wqkv_bf);
    hipLaunchKernelGGL(compute_u_partial, dim3(16),   dim3(256), 0, stream, wo, gw, upart);
    hipLaunchKernelGGL(finalize_u,        dim3(1),    dim3(256), 0, stream, upart, bo, gw, gb, u_ws, c0_ws);
    hipLaunchKernelGGL(attn_ctx_kernel,   dim3(G),    dim3(512), 0, stream,
                       x, wqkv_bf, bqkv, u_ws, c0_ws, wctx_ws, sg_ws);
    hipLaunchKernelGGL(outproj_kernel,    dim3(G/32), dim3(256), 0, stream,
                       wo_bf, wctx_ws, bo, sg_ws, out);
}

// Round 5
// 477.505 us; speedup vs baseline: 1.7104x; 1.0710x over previous
//
#include <hip/hip_runtime.h>
#include <stdint.h>

// AttentionReadout: G=1024 x N=64, D=512, H=8, hd=64. fp32 I/O, bf16 MFMA.
// v5: same structure as v4 (512-thr block/graph, x staged once to 149 KB LDS,
// head-pairs, gate-factorized via u = Wo^T gw) but the head-pair loop is
// FULLY UNROLLED so cctx[][] is statically indexed -> stays in VGPRs.
// (v4 lesson: dynamic index into reg array => scratch demotion, 132 MB of
// HBM spill writes, VGPR_Count 88.)

typedef __attribute__((ext_vector_type(8))) short short8;   // 8 bf16
typedef __attribute__((ext_vector_type(4))) float f32x4;    // MFMA C/D frag

#define D_ 512

// ---- ws layout (bytes) ----
#define WQKV_OFF   0u          // 1536*512 bf16 = 1572864
#define WO_OFF     1572864u    // 512*512 bf16  = 524288
#define UPART_OFF  2097152u    // 16*512 f32    = 32768
#define U_OFF      2129920u    // 512 f32       = 2048
#define C0_OFF     2131968u    // 64
#define SG_OFF     2132032u    // 1024 f32      = 4096
#define WCTX_OFF   2136128u    // 1024*512 bf16 = 1 MB (16B aligned)
// total ~3.2 MB

__device__ __forceinline__ unsigned short f2bf(float f) {
    union { float f; unsigned int u; } t; t.f = f;
    unsigned int u = t.u;
    return (unsigned short)((u + 0x7FFFu + ((u >> 16) & 1u)) >> 16);  // RNE
}

// ---- pre-pass 1: wqkv + wo fp32 -> bf16 ----
__global__ __launch_bounds__(256)
void convert_weights(const float* __restrict__ wqkv, const float* __restrict__ wo,
                     unsigned short* __restrict__ wbf) {
    const int i4 = blockIdx.x * 256 + threadIdx.x;          // 262144 float4 total
    float4 v;
    if (i4 < 196608) v = *(const float4*)(wqkv + (size_t)i4 * 4);
    else             v = *(const float4*)(wo   + (size_t)(i4 - 196608) * 4);
    unsigned short a0 = f2bf(v.x), a1 = f2bf(v.y), a2 = f2bf(v.z), a3 = f2bf(v.w);
    uint2 p; p.x = a0 | ((unsigned)a1 << 16); p.y = a2 | ((unsigned)a3 << 16);
    *(uint2*)(wbf + (size_t)i4 * 4) = p;
}

// ---- pre-pass 2a: u partials (16 blocks, e-split, coalesced row reads) ----
__global__ __launch_bounds__(256)
void compute_u_partial(const float* __restrict__ wo, const float* __restrict__ gw,
                       float* __restrict__ upart) {
    const int b = blockIdx.x;         // 16
    const int t = threadIdx.x;
    float a0 = 0.f, a1 = 0.f;
    #pragma unroll 4
    for (int e = b * 32; e < b * 32 + 32; ++e) {
        const float ge = gw[e];
        a0 += wo[(size_t)e * 512 + t]       * ge;
        a1 += wo[(size_t)e * 512 + t + 256] * ge;
    }
    upart[b * 512 + t] = a0; upart[b * 512 + t + 256] = a1;
}

// ---- pre-pass 2b: u = sum partials; c0 = bo.gw + gb ----
__global__ __launch_bounds__(256)
void finalize_u(const float* __restrict__ upart, const float* __restrict__ bo,
                const float* __restrict__ gw, const float* __restrict__ gb,
                float* __restrict__ u, float* __restrict__ c0) {
    const int t = threadIdx.x;
    float s0 = 0.f, s1 = 0.f;
    #pragma unroll
    for (int b = 0; b < 16; ++b) { s0 += upart[b*512 + t]; s1 += upart[b*512 + t + 256]; }
    u[t] = s0; u[t + 256] = s1;
    __shared__ float rb[256];
    rb[t] = bo[t] * gw[t] + bo[t + 256] * gw[t + 256];
    __syncthreads();
    for (int s = 128; s > 0; s >>= 1) { if (t < s) rb[t] += rb[t + s]; __syncthreads(); }
    if (t == 0) c0[0] = rb[0] + gb[0];
}

// ---- main: per-graph QKV + attention -> gates, wctx ----
__global__ __launch_bounds__(512, 2)
void attn_ctx_kernel(const float* __restrict__ x,             // [65536,512] f32
                     const unsigned short* __restrict__ wqkv, // [1536,512] bf16
                     const float* __restrict__ bqkv,          // [1536] f32
                     const float* __restrict__ u,             // [512] f32
                     const float* __restrict__ c0,            // [1] f32
                     unsigned short* __restrict__ wctx_ws,    // [1024,512] bf16
                     float* __restrict__ sumgate)             // [1024] f32
{
    __shared__ unsigned short xs[64][520];      // 66560 B, stride 1040B: 2-way (free)
    __shared__ unsigned short qbuf[2][64][72];  // 18432 B  q[head][n][d]
    __shared__ unsigned short kbuf[2][64][72];  // 18432 B  k[head][m][d]
    __shared__ unsigned short vbuf[2][64][72];  // 18432 B  vT[head][d][n]
    __shared__ unsigned short pbuf[2][64][72];  // 18432 B  P[head][n][m]
    __shared__ float fbuf[4][512];              // 8192 B   gated-ctx partials
    __shared__ float logit2[2][64];
    __shared__ float gatev[64];
    // total ~149.3 KB -> 1 block/CU, 8 waves

    const int g    = blockIdx.x;
    const int tid  = threadIdx.x;
    const int w    = tid >> 6;      // wave 0..7
    const int lane = tid & 63;
    const int l15  = lane & 15;
    const int quad = lane >> 4;

    // ---- stage x once: fp32 -> bf16 LDS ----
    #pragma unroll
    for (int i = 0; i < 16; ++i) {
        int idx = tid + i * 512;            // 8192 float4
        int row = idx >> 7;                 // 128 float4 per row
        int c4  = idx & 127;
        float4 v = *(const float4*)(x + ((size_t)(g*64 + row))*512 + c4*4);
        unsigned short a0 = f2bf(v.x), a1 = f2bf(v.y), a2 = f2bf(v.z), a3 = f2bf(v.w);
        uint2 p; p.x = a0 | ((unsigned)a1 << 16); p.y = a2 | ((unsigned)a3 << 16);
        *(uint2*)(&xs[row][c4*4]) = p;
    }
    if (tid < 128) ((float*)logit2)[tid] = 0.f;

    const int hs2  = w >> 2;         // head-slot this wave handles in attention
    const int row0 = (w & 3) << 4;   // its 16-row strip
    f32x4 cctx[4][4];                // ctx frags: [head-pair][dt] — statically indexed

    // precompute per-wave QKV tile mapping (hp-independent)
    int mj[3], hsj[3], rtj[3];
    #pragma unroll
    for (int j = 0; j < 3; ++j) {
        int t_ = w*3 + j;
        int c  = t_ >> 2; rtj[j] = t_ & 3;
        mj[j]  = c >> 1;  hsj[j] = c & 1;            // m: 0=q 1=k 2=v
    }

    #pragma unroll
    for (int hp = 0; hp < 4; ++hp) {
        __syncthreads();  // bufs safe to overwrite (also covers x-stage at hp=0)

        // ---- QKV: 24 row-tiles (q/k/v x 2 heads x 4), wave w owns tiles w*3+j ----
        f32x4 acc[3][4];
        #pragma unroll
        for (int j = 0; j < 3; ++j)
            #pragma unroll
            for (int nt = 0; nt < 4; ++nt) acc[j][nt] = (f32x4){0.f,0.f,0.f,0.f};

        const unsigned short* wr[3];
        #pragma unroll
        for (int j = 0; j < 3; ++j) {
            int head = hp*2 + hsj[j];
            wr[j] = wqkv + (size_t)(mj[j]*512 + head*64 + rtj[j]*16 + l15) * 512;
        }
        #pragma unroll 4
        for (int ks = 0; ks < 16; ++ks) {
            const int col = ks*32 + quad*8;
            short8 a0 = *(const short8*)(wr[0] + col);
            short8 a1 = *(const short8*)(wr[1] + col);
            short8 a2 = *(const short8*)(wr[2] + col);
            #pragma unroll
            for (int nt = 0; nt < 4; ++nt) {
                short8 b = *(const short8*)(&xs[nt*16 + l15][col]);
                acc[0][nt] = __builtin_amdgcn_mfma_f32_16x16x32_bf16(a0, b, acc[0][nt], 0,0,0);
                acc[1][nt] = __builtin_amdgcn_mfma_f32_16x16x32_bf16(a1, b, acc[1][nt], 0,0,0);
                acc[2][nt] = __builtin_amdgcn_mfma_f32_16x16x32_bf16(a2, b, acc[2][nt], 0,0,0);
            }
        }
        // write q,k ([n][d], packed) / v (transposed [d][n]) with bias
        #pragma unroll
        for (int j = 0; j < 3; ++j) {
            const int head  = hp*2 + hsj[j];
            const int dbase = mj[j]*512 + head*64 + rtj[j]*16 + quad*4;
            if (mj[j] == 2) {
                #pragma unroll
                for (int nt = 0; nt < 4; ++nt)
                    #pragma unroll
                    for (int r = 0; r < 4; ++r)
                        vbuf[hsj[j]][rtj[j]*16 + quad*4 + r][nt*16 + l15] =
                            f2bf(acc[j][nt][r] + bqkv[dbase + r]);
            } else {
                unsigned short (*dst)[72] = (mj[j] == 0) ? qbuf[hsj[j]] : kbuf[hsj[j]];
                #pragma unroll
                for (int nt = 0; nt < 4; ++nt) {
                    unsigned short tv[4];
                    #pragma unroll
                    for (int r = 0; r < 4; ++r) tv[r] = f2bf(acc[j][nt][r] + bqkv[dbase + r]);
                    uint2 pk; pk.x = tv[0] | ((unsigned)tv[1] << 16);
                    pk.y = tv[2] | ((unsigned)tv[3] << 16);
                    *(uint2*)(&dst[nt*16 + l15][rtj[j]*16 + quad*4]) = pk;
                }
            }
        }
        __syncthreads();

        // ---- scores + softmax: wave w -> head hs2, rows [row0, row0+16) ----
        f32x4 sacc[4];
        #pragma unroll
        for (int i = 0; i < 4; ++i) sacc[i] = (f32x4){0.f,0.f,0.f,0.f};
        #pragma unroll
        for (int ks = 0; ks < 2; ++ks) {
            short8 aq = *(const short8*)(&qbuf[hs2][row0 + l15][ks*32 + quad*8]);
            #pragma unroll
            for (int mt = 0; mt < 4; ++mt) {
                short8 bk = *(const short8*)(&kbuf[hs2][mt*16 + l15][ks*32 + quad*8]);
                sacc[mt] = __builtin_amdgcn_mfma_f32_16x16x32_bf16(aq, bk, sacc[mt], 0,0,0);
            }
        }
        float pv[4][4];
        #pragma unroll
        for (int r = 0; r < 4; ++r) {
            float m0 = -1e30f;
            #pragma unroll
            for (int mt = 0; mt < 4; ++mt) { pv[mt][r] = sacc[mt][r] * 0.125f; m0 = fmaxf(m0, pv[mt][r]); }
            m0 = fmaxf(m0, __shfl_xor(m0, 1));
            m0 = fmaxf(m0, __shfl_xor(m0, 2));
            m0 = fmaxf(m0, __shfl_xor(m0, 4));
            m0 = fmaxf(m0, __shfl_xor(m0, 8));
            float s = 0.f;
            #pragma unroll
            for (int mt = 0; mt < 4; ++mt) { float e = __expf(pv[mt][r] - m0); pv[mt][r] = e; s += e; }
            s += __shfl_xor(s, 1); s += __shfl_xor(s, 2); s += __shfl_xor(s, 4); s += __shfl_xor(s, 8);
            float inv = 1.0f / s;
            #pragma unroll
            for (int mt = 0; mt < 4; ++mt) pv[mt][r] *= inv;
        }
        #pragma unroll
        for (int mt = 0; mt < 4; ++mt)
            #pragma unroll
            for (int r = 0; r < 4; ++r)
                pbuf[hs2][row0 + quad*4 + r][mt*16 + l15] = f2bf(pv[mt][r]);
        __syncthreads();

        // ---- PV: ctx[n][d] = P @ v ----
        #pragma unroll
        for (int i = 0; i < 4; ++i) cctx[hp][i] = (f32x4){0.f,0.f,0.f,0.f};
        #pragma unroll
        for (int ks = 0; ks < 2; ++ks) {
            short8 ap = *(const short8*)(&pbuf[hs2][row0 + l15][ks*32 + quad*8]);
            #pragma unroll
            for (int dt = 0; dt < 4; ++dt) {
                short8 bv = *(const short8*)(&vbuf[hs2][dt*16 + l15][ks*32 + quad*8]);
                cctx[hp][dt] = __builtin_amdgcn_mfma_f32_16x16x32_bf16(ap, bv, cctx[hp][dt], 0,0,0);
            }
        }
        // gate-logit partials (fp32 ctx . u)
        {
            const int head2 = hp*2 + hs2;
            float uv[4];
            #pragma unroll
            for (int dt = 0; dt < 4; ++dt) uv[dt] = u[head2*64 + dt*16 + l15];
            #pragma unroll
            for (int r = 0; r < 4; ++r) {
                float s = cctx[hp][0][r]*uv[0] + cctx[hp][1][r]*uv[1]
                        + cctx[hp][2][r]*uv[2] + cctx[hp][3][r]*uv[3];
                s += __shfl_xor(s, 1); s += __shfl_xor(s, 2);
                s += __shfl_xor(s, 4); s += __shfl_xor(s, 8);
                if (l15 == 0) logit2[hs2][row0 + quad*4 + r] += s;  // wave-exclusive slots
            }
        }
    }

    __syncthreads();   // logit2 complete
    if (tid < 64) {
        float lg = logit2[0][tid] + logit2[1][tid] + c0[0];
        float gt = 1.0f / (1.0f + __expf(-lg));
        gatev[tid] = gt;
        float s = gt;
        s += __shfl_xor(s, 1);  s += __shfl_xor(s, 2);  s += __shfl_xor(s, 4);
        s += __shfl_xor(s, 8);  s += __shfl_xor(s, 16); s += __shfl_xor(s, 32);
        if (tid == 0) sumgate[g] = s;
    }
    __syncthreads();

    // ---- gated reduction from register ctx: wctx[d] = sum_n gate[n] ctx[n][d] ----
    {
        float gv[4];
        #pragma unroll
        for (int r = 0; r < 4; ++r) gv[r] = gatev[row0 + quad*4 + r];
        #pragma unroll
        for (int hp = 0; hp < 4; ++hp) {
            const int head2 = hp*2 + hs2;
            #pragma unroll
            for (int dt = 0; dt < 4; ++dt) {
                float s = cctx[hp][dt][0]*gv[0] + cctx[hp][dt][1]*gv[1]
                        + cctx[hp][dt][2]*gv[2] + cctx[hp][dt][3]*gv[3];
                s += __shfl_xor(s, 16); s += __shfl_xor(s, 32);   // sum over quads
                if (lane < 16) fbuf[w & 3][head2*64 + dt*16 + lane] = s;
            }
        }
    }
    __syncthreads();
    {
        float vs = fbuf[0][tid] + fbuf[1][tid] + fbuf[2][tid] + fbuf[3][tid];
        wctx_ws[(size_t)g*512 + tid] = f2bf(vs);
    }
}

// ---- final out-projection: out[g][e] = wctx[g,:].Wo[e,:] + sumgate[g]*bo[e] ----
__global__ __launch_bounds__(256, 4)
void outproj_kernel(const unsigned short* __restrict__ wo_bf,   // [512,512] bf16
                    const unsigned short* __restrict__ wctx_bf, // [1024,512] bf16
                    const float* __restrict__ bo,               // [512] f32
                    const float* __restrict__ sumgate,          // [1024] f32
                    float* __restrict__ out)                    // [1024,512] f32
{
    const int tid  = threadIdx.x;
    const int w    = tid >> 6;
    const int lane = tid & 63;
    const int l15  = lane & 15;
    const int quad = lane >> 4;
    const int g0   = blockIdx.x * 32;

    f32x4 oac[8][2];
    #pragma unroll
    for (int et = 0; et < 8; ++et)
        #pragma unroll
        for (int mt = 0; mt < 2; ++mt)
            oac[et][mt] = (f32x4){0.f,0.f,0.f,0.f};

    #pragma unroll 4
    for (int ks = 0; ks < 16; ++ks) {
        const int col = ks*32 + quad*8;
        short8 a0 = *(const short8*)(wctx_bf + (size_t)(g0 + l15)*D_      + col);
        short8 a1 = *(const short8*)(wctx_bf + (size_t)(g0 + 16 + l15)*D_ + col);
        #pragma unroll
        for (int et = 0; et < 8; ++et) {
            short8 b = *(const short8*)(wo_bf + (size_t)(w*128 + et*16 + l15)*D_ + col);
            oac[et][0] = __builtin_amdgcn_mfma_f32_16x16x32_bf16(a0, b, oac[et][0], 0,0,0);
            oac[et][1] = __builtin_amdgcn_mfma_f32_16x16x32_bf16(a1, b, oac[et][1], 0,0,0);
        }
    }
    #pragma unroll
    for (int et = 0; et < 8; ++et) {
        const int e = w*128 + et*16 + l15;
        const float bov = bo[e];
        #pragma unroll
        for (int mt = 0; mt < 2; ++mt)
            #pragma unroll
            for (int r = 0; r < 4; ++r) {
                const int gg = g0 + mt*16 + quad*4 + r;
                out[(size_t)gg*D_ + e] = oac[et][mt][r] + sumgate[gg] * bov;
            }
    }
}

extern "C" void kernel_launch(void* const* d_in, const int* in_sizes, int n_in,
                              void* d_out, int out_size, void* d_ws, size_t ws_size,
                              hipStream_t stream) {
    const float* x    = (const float*)d_in[0];
    // d_in[1] = batch (int64) — unused: graphs are equal-sized (64 nodes)
    const float* wqkv = (const float*)d_in[2];
    const float* bqkv = (const float*)d_in[3];
    const float* wo   = (const float*)d_in[4];
    const float* bo   = (const float*)d_in[5];
    const float* gw   = (const float*)d_in[6];
    const float* gb   = (const float*)d_in[7];
    float* out = (float*)d_out;

    char* ws = (char*)d_ws;
    unsigned short* wqkv_bf = (unsigned short*)(ws + WQKV_OFF);
    unsigned short* wo_bf   = (unsigned short*)(ws + WO_OFF);
    float*          upart   = (float*)(ws + UPART_OFF);
    float*          u_ws    = (float*)(ws + U_OFF);
    float*          c0_ws   = (float*)(ws + C0_OFF);
    float*          sg_ws   = (float*)(ws + SG_OFF);
    unsigned short* wctx_ws = (unsigned short*)(ws + WCTX_OFF);

    const int total = in_sizes[0] / D_;  // 65536 nodes
    const int G     = total / 64;        // 1024 graphs

    hipLaunchKernelGGL(convert_weights,   dim3(1024), dim3(256), 0, stream, wqkv, wo, wqkv_bf);
    hipLaunchKernelGGL(compute_u_partial, dim3(16),   dim3(256), 0, stream, wo, gw, upart);
    hipLaunchKernelGGL(finalize_u,        dim3(1),    dim3(256), 0, stream, upart, bo, gw, gb, u_ws, c0_ws);
    hipLaunchKernelGGL(attn_ctx_kernel,   dim3(G),    dim3(512), 0, stream,
                       x, wqkv_bf, bqkv, u_ws, c0_ws, wctx_ws, sg_ws);
    hipLaunchKernelGGL(outproj_kernel,    dim3(G/32), dim3(256), 0, stream,
                       wo_bf, wctx_ws, bo, sg_ws, out);
}

// Round 6
// 445.788 us; speedup vs baseline: 1.8321x; 1.0711x over previous
//
#include <hip/hip_runtime.h>
#include <stdint.h>

// AttentionReadout: G=1024 x N=64, D=512, H=8, hd=64. fp32 I/O, bf16 MFMA.
// v6: BARRIER-FREE middle. 512-thr block per graph; wave w owns head w fully
// (QKV -> scores -> softmax -> PV). Only 3 __syncthreads total (x-stage + gate
// epilogue). q/k MFMA C-layout -> score-fragment conversion done in-register
// via quad shuffles; v/P round-trip a 9 KB per-wave LDS scratch (in-order DS).
// v5 lesson: 13 barriers x 1 block/CU = all pipes <16% busy.

typedef __attribute__((ext_vector_type(8))) short short8;   // 8 bf16
typedef __attribute__((ext_vector_type(4))) float f32x4;    // MFMA C/D frag

#define D_ 512

// ---- ws layout (bytes) ----
#define WQKV_OFF   0u          // 1536*512 bf16 = 1572864
#define WO_OFF     1572864u    // 512*512 bf16  = 524288
#define UPART_OFF  2097152u    // 16*512 f32    = 32768
#define U_OFF      2129920u    // 512 f32       = 2048
#define C0_OFF     2131968u    // 64
#define SG_OFF     2132032u    // 1024 f32      = 4096
#define WCTX_OFF   2136128u    // 1024*512 bf16 = 1 MB (16B aligned)

__device__ __forceinline__ unsigned short f2bf(float f) {
    union { float f; unsigned int u; } t; t.f = f;
    unsigned int u = t.u;
    return (unsigned short)((u + 0x7FFFu + ((u >> 16) & 1u)) >> 16);  // RNE
}
__device__ __forceinline__ unsigned pack2(float a, float b) {
    return (unsigned)f2bf(a) | ((unsigned)f2bf(b) << 16);
}

// ---- pre-pass 1: wqkv + wo fp32 -> bf16 ----
__global__ __launch_bounds__(256)
void convert_weights(const float* __restrict__ wqkv, const float* __restrict__ wo,
                     unsigned short* __restrict__ wbf) {
    const int i4 = blockIdx.x * 256 + threadIdx.x;          // 262144 float4 total
    float4 v;
    if (i4 < 196608) v = *(const float4*)(wqkv + (size_t)i4 * 4);
    else             v = *(const float4*)(wo   + (size_t)(i4 - 196608) * 4);
    uint2 p; p.x = pack2(v.x, v.y); p.y = pack2(v.z, v.w);
    *(uint2*)(wbf + (size_t)i4 * 4) = p;
}

// ---- pre-pass 2a: u partials (16 blocks) ----
__global__ __launch_bounds__(256)
void compute_u_partial(const float* __restrict__ wo, const float* __restrict__ gw,
                       float* __restrict__ upart) {
    const int b = blockIdx.x;
    const int t = threadIdx.x;
    float a0 = 0.f, a1 = 0.f;
    #pragma unroll 4
    for (int e = b * 32; e < b * 32 + 32; ++e) {
        const float ge = gw[e];
        a0 += wo[(size_t)e * 512 + t]       * ge;
        a1 += wo[(size_t)e * 512 + t + 256] * ge;
    }
    upart[b * 512 + t] = a0; upart[b * 512 + t + 256] = a1;
}

// ---- pre-pass 2b: u = sum partials; c0 = bo.gw + gb ----
__global__ __launch_bounds__(256)
void finalize_u(const float* __restrict__ upart, const float* __restrict__ bo,
                const float* __restrict__ gw, const float* __restrict__ gb,
                float* __restrict__ u, float* __restrict__ c0) {
    const int t = threadIdx.x;
    float s0 = 0.f, s1 = 0.f;
    #pragma unroll
    for (int b = 0; b < 16; ++b) { s0 += upart[b*512 + t]; s1 += upart[b*512 + t + 256]; }
    u[t] = s0; u[t + 256] = s1;
    __shared__ float rb[256];
    rb[t] = bo[t] * gw[t] + bo[t + 256] * gw[t + 256];
    __syncthreads();
    for (int s = 128; s > 0; s >>= 1) { if (t < s) rb[t] += rb[t + s]; __syncthreads(); }
    if (t == 0) c0[0] = rb[0] + gb[0];
}

union U8 { unsigned u[4]; short8 s; };

// ---- main: per-graph, wave-per-head, barrier-free middle ----
__global__ __launch_bounds__(512, 2)
void attn_ctx_kernel(const float* __restrict__ x,             // [65536,512] f32
                     const unsigned short* __restrict__ wqkv, // [1536,512] bf16
                     const float* __restrict__ bqkv,          // [1536] f32
                     const float* __restrict__ u,             // [512] f32
                     const float* __restrict__ c0,            // [1] f32
                     unsigned short* __restrict__ wctx_ws,    // [1024,512] bf16
                     float* __restrict__ sumgate)             // [1024] f32
{
    __shared__ unsigned short xs[64][520];     // 66560 B  x slab (bf16)
    __shared__ unsigned short scr[8][64][72];  // 73728 B  per-wave scratch (vT then P)
    __shared__ float logitp[8][64];            // 2048 B
    __shared__ float gatev[64];                // 256 B
    // total 142592 B -> 1 block/CU, 8 waves (2/SIMD)

    const int g    = blockIdx.x;
    const int tid  = threadIdx.x;
    const int w    = tid >> 6;      // wave = head
    const int lane = tid & 63;
    const int l15  = lane & 15;
    const int quad = lane >> 4;

    // ---- stage x once: fp32 -> bf16 LDS (only block-wide phase) ----
    #pragma unroll
    for (int i = 0; i < 16; ++i) {
        int idx = tid + i * 512;
        int row = idx >> 7;
        int c4  = idx & 127;
        float4 v = *(const float4*)(x + ((size_t)(g*64 + row))*512 + c4*4);
        uint2 p; p.x = pack2(v.x, v.y); p.y = pack2(v.z, v.w);
        *(uint2*)(&xs[row][c4*4]) = p;
    }
    __syncthreads();

    const int h = w;
    unsigned short (*S)[72] = scr[w];

    // ======== QKV for head h (K=512), building score frags in-register ========
    U8 qA[4][2], kB[4][2];   // [n-strip][ks2] A/B frags for scores
    #pragma unroll
    for (int dt = 0; dt < 4; ++dt) {
        f32x4 aq[4], ak[4], av[4];
        #pragma unroll
        for (int nt = 0; nt < 4; ++nt) {
            aq[nt] = (f32x4){0.f,0.f,0.f,0.f};
            ak[nt] = (f32x4){0.f,0.f,0.f,0.f};
            av[nt] = (f32x4){0.f,0.f,0.f,0.f};
        }
        const unsigned short* wq = wqkv + (size_t)(          h*64 + dt*16 + l15) * 512;
        const unsigned short* wk = wqkv + (size_t)( 512 +    h*64 + dt*16 + l15) * 512;
        const unsigned short* wv = wqkv + (size_t)(1024 +    h*64 + dt*16 + l15) * 512;
        #pragma unroll 4
        for (int ks = 0; ks < 16; ++ks) {
            const int col = ks*32 + quad*8;
            short8 a0 = *(const short8*)(wq + col);
            short8 a1 = *(const short8*)(wk + col);
            short8 a2 = *(const short8*)(wv + col);
            #pragma unroll
            for (int nt = 0; nt < 4; ++nt) {
                short8 b = *(const short8*)(&xs[nt*16 + l15][col]);
                aq[nt] = __builtin_amdgcn_mfma_f32_16x16x32_bf16(a0, b, aq[nt], 0,0,0);
                ak[nt] = __builtin_amdgcn_mfma_f32_16x16x32_bf16(a1, b, ak[nt], 0,0,0);
                av[nt] = __builtin_amdgcn_mfma_f32_16x16x32_bf16(a2, b, av[nt], 0,0,0);
            }
        }
        // biases for this lane's d = dt*16 + quad*4 + r
        float bq[4], bk2[4], bv2[4];
        #pragma unroll
        for (int r = 0; r < 4; ++r) {
            bq[r]  = bqkv[          h*64 + dt*16 + quad*4 + r];
            bk2[r] = bqkv[ 512 +    h*64 + dt*16 + quad*4 + r];
            bv2[r] = bqkv[1024 +    h*64 + dt*16 + quad*4 + r];
        }
        const bool take = ((quad >> 1) == (dt & 1));
        const int  ks2  = dt >> 1;
        #pragma unroll
        for (int nt = 0; nt < 4; ++nt) {
            // q/k C-layout [d][n] -> frag [n][d] via quad shuffles
            unsigned q01 = pack2(aq[nt][0]+bq[0],  aq[nt][1]+bq[1]);
            unsigned q23 = pack2(aq[nt][2]+bq[2],  aq[nt][3]+bq[3]);
            unsigned k01 = pack2(ak[nt][0]+bk2[0], ak[nt][1]+bk2[1]);
            unsigned k23 = pack2(ak[nt][2]+bk2[2], ak[nt][3]+bk2[3]);
            #pragma unroll
            for (int j = 0; j < 4; ++j) {
                int srcl = ((quad & 1)*2 + (j >> 1))*16 + l15;
                unsigned tq = (unsigned)__shfl((int)((j & 1) ? q23 : q01), srcl);
                unsigned tk = (unsigned)__shfl((int)((j & 1) ? k23 : k01), srcl);
                if (take) { qA[nt][ks2].u[j] = tq; kB[nt][ks2].u[j] = tk; }
            }
            // v (+bias) -> scratch as vT[d][m]
            #pragma unroll
            for (int r = 0; r < 4; ++r)
                S[dt*16 + quad*4 + r][nt*16 + l15] = f2bf(av[nt][r] + bv2[r]);
        }
    }

    // ======== scores S[n][m] = q.k^T / 8 (full 64x64 per wave) ========
    f32x4 sacc[4][4];
    #pragma unroll
    for (int a = 0; a < 4; ++a)
        #pragma unroll
        for (int b = 0; b < 4; ++b) sacc[a][b] = (f32x4){0.f,0.f,0.f,0.f};
    #pragma unroll
    for (int ks2 = 0; ks2 < 2; ++ks2)
        #pragma unroll
        for (int a = 0; a < 4; ++a)
            #pragma unroll
            for (int b = 0; b < 4; ++b)
                sacc[a][b] = __builtin_amdgcn_mfma_f32_16x16x32_bf16(
                                 qA[a][ks2].s, kB[b][ks2].s, sacc[a][b], 0,0,0);

    // ======== softmax over m (per row n = a*16 + quad*4 + r) ========
    #pragma unroll
    for (int a = 0; a < 4; ++a) {
        #pragma unroll
        for (int r = 0; r < 4; ++r) {
            float m0 = -1e30f;
            #pragma unroll
            for (int b = 0; b < 4; ++b) { sacc[a][b][r] *= 0.125f; m0 = fmaxf(m0, sacc[a][b][r]); }
            m0 = fmaxf(m0, __shfl_xor(m0, 1));
            m0 = fmaxf(m0, __shfl_xor(m0, 2));
            m0 = fmaxf(m0, __shfl_xor(m0, 4));
            m0 = fmaxf(m0, __shfl_xor(m0, 8));
            float s = 0.f;
            #pragma unroll
            for (int b = 0; b < 4; ++b) { float e = __expf(sacc[a][b][r] - m0); sacc[a][b][r] = e; s += e; }
            s += __shfl_xor(s, 1); s += __shfl_xor(s, 2); s += __shfl_xor(s, 4); s += __shfl_xor(s, 8);
            float inv = 1.0f / s;
            #pragma unroll
            for (int b = 0; b < 4; ++b) sacc[a][b][r] *= inv;
        }
    }

    // ======== extract vA frags BEFORE overwriting scratch with P ========
    U8 vA[4][2];
    #pragma unroll
    for (int dtile = 0; dtile < 4; ++dtile)
        #pragma unroll
        for (int ks2 = 0; ks2 < 2; ++ks2)
            vA[dtile][ks2].s = *(const short8*)(&S[dtile*16 + l15][ks2*32 + quad*8]);

    // ======== P -> scratch [n][m] (scalar b16; in-order DS after vA reads) ========
    #pragma unroll
    for (int a = 0; a < 4; ++a)
        #pragma unroll
        for (int b = 0; b < 4; ++b)
            #pragma unroll
            for (int r = 0; r < 4; ++r)
                S[a*16 + quad*4 + r][b*16 + l15] = f2bf(sacc[a][b][r]);

    U8 pB[4][2];
    #pragma unroll
    for (int a = 0; a < 4; ++a)
        #pragma unroll
        for (int ks2 = 0; ks2 < 2; ++ks2)
            pB[a][ks2].s = *(const short8*)(&S[a*16 + l15][ks2*32 + quad*8]);

    // ======== PV: ctxT[d][n] = vT @ P^T ========
    f32x4 cacc[4][4];   // [dtile][a]; lane: d = dtile*16+quad*4+r, n = a*16+l15
    #pragma unroll
    for (int dtile = 0; dtile < 4; ++dtile)
        #pragma unroll
        for (int a = 0; a < 4; ++a) cacc[dtile][a] = (f32x4){0.f,0.f,0.f,0.f};
    #pragma unroll
    for (int ks2 = 0; ks2 < 2; ++ks2)
        #pragma unroll
        for (int dtile = 0; dtile < 4; ++dtile)
            #pragma unroll
            for (int a = 0; a < 4; ++a)
                cacc[dtile][a] = __builtin_amdgcn_mfma_f32_16x16x32_bf16(
                                     vA[dtile][ks2].s, pB[a][ks2].s, cacc[dtile][a], 0,0,0);

    // ======== gate-logit partials: logit[n] += sum_d ctx[n][d] u[h*64+d] ========
    {
        float uv[4][4];
        #pragma unroll
        for (int dtile = 0; dtile < 4; ++dtile)
            #pragma unroll
            for (int r = 0; r < 4; ++r)
                uv[dtile][r] = u[h*64 + dtile*16 + quad*4 + r];
        #pragma unroll
        for (int a = 0; a < 4; ++a) {
            float s = 0.f;
            #pragma unroll
            for (int dtile = 0; dtile < 4; ++dtile)
                #pragma unroll
                for (int r = 0; r < 4; ++r)
                    s += cacc[dtile][a][r] * uv[dtile][r];
            s += __shfl_xor(s, 16); s += __shfl_xor(s, 32);   // sum over quads
            if (quad == 0) logitp[w][a*16 + l15] = s;
        }
    }
    __syncthreads();   // logitp complete (all waves)

    if (tid < 64) {
        float lg = c0[0];
        #pragma unroll
        for (int ww = 0; ww < 8; ++ww) lg += logitp[ww][tid];
        float gt = 1.0f / (1.0f + __expf(-lg));
        gatev[tid] = gt;
        float s = gt;
        s += __shfl_xor(s, 1);  s += __shfl_xor(s, 2);  s += __shfl_xor(s, 4);
        s += __shfl_xor(s, 8);  s += __shfl_xor(s, 16); s += __shfl_xor(s, 32);
        if (tid == 0) sumgate[g] = s;
    }
    __syncthreads();

    // ======== wctx[d] = sum_n gate[n] ctx[n][d] (wave-exclusive d range) ========
    {
        float gv[4];
        #pragma unroll
        for (int a = 0; a < 4; ++a) gv[a] = gatev[a*16 + l15];
        #pragma unroll
        for (int dtile = 0; dtile < 4; ++dtile) {
            float sr[4];
            #pragma unroll
            for (int r = 0; r < 4; ++r) {
                float s = cacc[dtile][0][r]*gv[0] + cacc[dtile][1][r]*gv[1]
                        + cacc[dtile][2][r]*gv[2] + cacc[dtile][3][r]*gv[3];
                s += __shfl_xor(s, 1); s += __shfl_xor(s, 2);
                s += __shfl_xor(s, 4); s += __shfl_xor(s, 8);   // sum over l15
                sr[r] = s;
            }
            if (l15 == 0) {
                uint2 pk; pk.x = pack2(sr[0], sr[1]); pk.y = pack2(sr[2], sr[3]);
                *(uint2*)(wctx_ws + (size_t)g*512 + h*64 + dtile*16 + quad*4) = pk;
            }
        }
    }
}

// ---- final out-projection: out[g][e] = wctx[g,:].Wo[e,:] + sumgate[g]*bo[e] ----
__global__ __launch_bounds__(256, 4)
void outproj_kernel(const unsigned short* __restrict__ wo_bf,   // [512,512] bf16
                    const unsigned short* __restrict__ wctx_bf, // [1024,512] bf16
                    const float* __restrict__ bo,               // [512] f32
                    const float* __restrict__ sumgate,          // [1024] f32
                    float* __restrict__ out)                    // [1024,512] f32
{
    const int tid  = threadIdx.x;
    const int w    = tid >> 6;
    const int lane = tid & 63;
    const int l15  = lane & 15;
    const int quad = lane >> 4;
    const int g0   = blockIdx.x * 32;

    f32x4 oac[8][2];
    #pragma unroll
    for (int et = 0; et < 8; ++et)
        #pragma unroll
        for (int mt = 0; mt < 2; ++mt)
            oac[et][mt] = (f32x4){0.f,0.f,0.f,0.f};

    #pragma unroll 4
    for (int ks = 0; ks < 16; ++ks) {
        const int col = ks*32 + quad*8;
        short8 a0 = *(const short8*)(wctx_bf + (size_t)(g0 + l15)*D_      + col);
        short8 a1 = *(const short8*)(wctx_bf + (size_t)(g0 + 16 + l15)*D_ + col);
        #pragma unroll
        for (int et = 0; et < 8; ++et) {
            short8 b = *(const short8*)(wo_bf + (size_t)(w*128 + et*16 + l15)*D_ + col);
            oac[et][0] = __builtin_amdgcn_mfma_f32_16x16x32_bf16(a0, b, oac[et][0], 0,0,0);
            oac[et][1] = __builtin_amdgcn_mfma_f32_16x16x32_bf16(a1, b, oac[et][1], 0,0,0);
        }
    }
    #pragma unroll
    for (int et = 0; et < 8; ++et) {
        const int e = w*128 + et*16 + l15;
        const float bov = bo[e];
        #pragma unroll
        for (int mt = 0; mt < 2; ++mt)
            #pragma unroll
            for (int r = 0; r < 4; ++r) {
                const int gg = g0 + mt*16 + quad*4 + r;
                out[(size_t)gg*D_ + e] = oac[et][mt][r] + sumgate[gg] * bov;
            }
    }
}

extern "C" void kernel_launch(void* const* d_in, const int* in_sizes, int n_in,
                              void* d_out, int out_size, void* d_ws, size_t ws_size,
                              hipStream_t stream) {
    const float* x    = (const float*)d_in[0];
    // d_in[1] = batch (int64) — unused: graphs are equal-sized (64 nodes)
    const float* wqkv = (const float*)d_in[2];
    const float* bqkv = (const float*)d_in[3];
    const float* wo   = (const float*)d_in[4];
    const float* bo   = (const float*)d_in[5];
    const float* gw   = (const float*)d_in[6];
    const float* gb   = (const float*)d_in[7];
    float* out = (float*)d_out;

    char* ws = (char*)d_ws;
    unsigned short* wqkv_bf = (unsigned short*)(ws + WQKV_OFF);
    unsigned short* wo_bf   = (unsigned short*)(ws + WO_OFF);
    float*          upart   = (float*)(ws + UPART_OFF);
    float*          u_ws    = (float*)(ws + U_OFF);
    float*          c0_ws   = (float*)(ws + C0_OFF);
    float*          sg_ws   = (float*)(ws + SG_OFF);
    unsigned short* wctx_ws = (unsigned short*)(ws + WCTX_OFF);

    const int total = in_sizes[0] / D_;  // 65536 nodes
    const int G     = total / 64;        // 1024 graphs

    hipLaunchKernelGGL(convert_weights,   dim3(1024), dim3(256), 0, stream, wqkv, wo, wqkv_bf);
    hipLaunchKernelGGL(compute_u_partial, dim3(16),   dim3(256), 0, stream, wo, gw, upart);
    hipLaunchKernelGGL(finalize_u,        dim3(1),    dim3(256), 0, stream, upart, bo, gw, gb, u_ws, c0_ws);
    hipLaunchKernelGGL(attn_ctx_kernel,   dim3(G),    dim3(512), 0, stream,
                       x, wqkv_bf, bqkv, u_ws, c0_ws, wctx_ws, sg_ws);
    hipLaunchKernelGGL(outproj_kernel,    dim3(G/32), dim3(256), 0, stream,
                       wo_bf, wctx_ws, bo, sg_ws, out);
}